// Round 4
// baseline (5867.740 us; speedup 1.0000x reference)
//
#include <hip/hip_runtime.h>

typedef _Float16 half_t;
typedef _Float16 f16x2 __attribute__((ext_vector_type(2)));
typedef _Float16 f16x8 __attribute__((ext_vector_type(8)));
typedef float f32x4 __attribute__((ext_vector_type(4)));

#define B_SZ 64
#define T_SZ 2048
#define F_SZ 256
#define H_SZ 512
#define O_SZ 128
#define NCH 32      // chunks
#define CH 64       // timesteps per chunk

#if defined(__has_builtin)
#if __has_builtin(__builtin_amdgcn_fdot2)
#define HAS_FDOT2 1
#endif
#if __has_builtin(__builtin_amdgcn_rcpf)
#define HAS_RCPF 1
#endif
#endif
#ifndef HAS_FDOT2
#define HAS_FDOT2 0
#endif
#ifndef HAS_RCPF
#define HAS_RCPF 0
#endif

static __device__ __forceinline__ float fdot2(unsigned int w, unsigned int h, float acc) {
#if HAS_FDOT2
    return __builtin_amdgcn_fdot2(__builtin_bit_cast(f16x2, w), __builtin_bit_cast(f16x2, h), acc, false);
#else
    f16x2 wv = __builtin_bit_cast(f16x2, w);
    f16x2 hv = __builtin_bit_cast(f16x2, h);
    return acc + (float)wv[0] * (float)hv[0] + (float)wv[1] * (float)hv[1];
#endif
}

static __device__ __forceinline__ unsigned int pack_pair(float a, float b) {
    f16x2 p;
    p[0] = (half_t)a;
    p[1] = (half_t)b;
    return __builtin_bit_cast(unsigned int, p);
}

static __device__ __forceinline__ float fast_rcp(float x) {
#if HAS_RCPF
    return __builtin_amdgcn_rcpf(x);
#else
    return 1.0f / x;
#endif
}

// DPP-based in-wave add: x + x[lane ^ pattern], VALU pipe only (no LDS).
// 0x0B1 = quad_perm [1,0,3,2]  (xor 1)
// 0x04E = quad_perm [2,3,0,1]  (xor 2)
// 0x141 = row_half_mirror      (xor 7 within each 8-lane half-row)
template<int CTRL>
static __device__ __forceinline__ float dpp_add(float x) {
    int y = __builtin_amdgcn_mov_dpp(__builtin_bit_cast(int, x), CTRL, 0xF, 0xF, true);
    return x + __builtin_bit_cast(float, y);
}

// Per-step barrier: LDS-only drain. __syncthreads() would add a vmcnt(0)
// drain of the in-flight xp prefetch / res store every step.
static __device__ __forceinline__ void step_barrier() {
    __builtin_amdgcn_sched_barrier(0);
    asm volatile("s_waitcnt lgkmcnt(0)" ::: "memory");
    __builtin_amdgcn_s_barrier();
    __builtin_amdgcn_sched_barrier(0);
}

// ---------------- prep ----------------

__global__ void cvt_f32_f16(const float* __restrict__ src, half_t* __restrict__ dst, int n) {
    int i = blockIdx.x * 256 + threadIdx.x;
    if (i < n) dst[i] = (half_t)src[i];
}

__global__ void zero_flags(unsigned int* __restrict__ p, int n) {
    int i = blockIdx.x * 256 + threadIdx.x;
    if (i < n) p[i] = 0u;
}

// ---------------- xp0 GEMM (MFMA f16), layer-0 input projection ----------------
template<bool A_F32, int K>
__global__ __launch_bounds__(256) void gemm_xp(const void* __restrict__ Aptr,
                                               const half_t* __restrict__ Bw,
                                               const float* __restrict__ bias1,
                                               const float* __restrict__ bias2,
                                               half_t* __restrict__ Cout)
{
    const int nt   = blockIdx.x & 7;
    const int mt   = blockIdx.x >> 3;
    const int wave = threadIdx.x >> 6;
    const int lane = threadIdx.x & 63;
    const int mrow = mt * 64 + wave * 16 + (lane & 15);
    const int koff = (lane >> 4) * 8;

    f32x4 acc[4];
#pragma unroll
    for (int i = 0; i < 4; i++) acc[i] = (f32x4){0.f, 0.f, 0.f, 0.f};

#pragma unroll 2
    for (int k0 = 0; k0 < K; k0 += 32) {
        f16x8 a;
        if (A_F32) {
            const float* ap = (const float*)Aptr + (size_t)mrow * K + (k0 + koff);
            float4 v0 = ((const float4*)ap)[0];
            float4 v1 = ((const float4*)ap)[1];
            a[0] = (half_t)v0.x; a[1] = (half_t)v0.y; a[2] = (half_t)v0.z; a[3] = (half_t)v0.w;
            a[4] = (half_t)v1.x; a[5] = (half_t)v1.y; a[6] = (half_t)v1.z; a[7] = (half_t)v1.w;
        } else {
            const half_t* ap = (const half_t*)Aptr + (size_t)mrow * K + (k0 + koff);
            a = *(const f16x8*)ap;
        }
#pragma unroll
        for (int cb = 0; cb < 4; cb++) {
            const int col = nt * 64 + cb * 16 + (lane & 15);
            f16x8 bfrag = *(const f16x8*)(Bw + (size_t)col * K + (k0 + koff));
            acc[cb] = __builtin_amdgcn_mfma_f32_16x16x32_f16(a, bfrag, acc[cb], 0, 0, 0);
        }
    }
    const int rbase = mt * 64 + wave * 16 + (lane >> 4) * 4;
#pragma unroll
    for (int cb = 0; cb < 4; cb++) {
        const int col = nt * 64 + cb * 16 + (lane & 15);
        const float bsum = bias1[col] + bias2[col];
#pragma unroll
        for (int r = 0; r < 4; r++) {
            Cout[(size_t)(rbase + r) * H_SZ + col] = (half_t)(acc[cb][r] + bsum);
        }
    }
}

// ---------------- mega-kernel: pipelined 2-layer RNN ----------------
// 192 blocks x 256 THREADS (4 waves = 1 wave/SIMD -> 512 regs/wave),
// role = blockIdx.x % 3, b = blockIdx.x / 3 (same 3-role chunk pipeline).
//
// Rec decomposition: wave s owns rows 128s..128s+127. Lane l = 8q + sp
// computes rows 128s+16q+{0..15} over K-cols 64sp..64sp+63. 28 of 32
// f16-pair columns live in VGPR+AGPR (448 u32; fdot2 reads AGPRs
// directly), 4 pairs stream from LDS (16 b128/thread/step vs 96 KB/step
// through LDS at 2-wave occupancy before). Row sums reduced across the 8
// sp-lanes with 3 DPP adds; each lane keeps rows 2sp,2sp+1 via cndmask
// tree -> thread produces elements e0=128s+16q+2sp and e0+1 (packed b32
// xp loads / res stores / h writes). One lgkm-only barrier per step.
//
// Requires all 192 blocks co-resident (flag spin) -> cooperative launch.
__global__ __launch_bounds__(256, 1)
void rnn_mega(half_t* bufA, half_t* bufB,
              const float* __restrict__ Whh0, const float* __restrict__ Whh1,
              const half_t* __restrict__ Wih1h,
              const float* __restrict__ h0_0, const float* __restrict__ h0_1,
              const float* __restrict__ b_ih1, const float* __restrict__ b_hh1,
              float* hT,
              unsigned int* flags0, unsigned int* flags1)
{
    __shared__ __align__(16) uint4 wlds[16 * 256];      // 64 KB (W overflow: 4 pairs x 16 rows)
    __shared__ __align__(16) half_t hpad[2][8 * 72];    // 2.25 KB (h, padded slices)

    const int role = blockIdx.x % 3;
    const int b    = blockIdx.x / 3;
    const int tid  = threadIdx.x;
    const int l    = tid & 63;
    const int s    = tid >> 6;          // wave 0..3

    if (role == 1) {
        // ---------- xp1 chunk-GEMM producer (4 waves x 128 cols) ----------
        const int w = s, lane = l;
        const int koff = (lane >> 4) * 8;
        for (int chunk = 0; chunk < NCH; chunk++) {
            if (tid == 0) {
                while (__hip_atomic_load(&flags0[b * NCH + chunk], __ATOMIC_ACQUIRE,
                                         __HIP_MEMORY_SCOPE_AGENT) == 0u)
                    __builtin_amdgcn_s_sleep(2);
            }
            __syncthreads();   // all threads gated; acquire-inv done by wave 0
            const int t0 = chunk * CH;

            f32x4 gac[4][8];
#pragma unroll
            for (int rt = 0; rt < 4; rt++)
#pragma unroll
                for (int cb = 0; cb < 8; cb++) gac[rt][cb] = (f32x4){0.f, 0.f, 0.f, 0.f};

#pragma unroll 1
            for (int k0 = 0; k0 < H_SZ; k0 += 32) {
                f16x8 bf[8];
#pragma unroll
                for (int cb = 0; cb < 8; cb++)
                    bf[cb] = *(const f16x8*)(Wih1h +
                              (size_t)(128 * w + 16 * cb + (lane & 15)) * H_SZ + k0 + koff);
#pragma unroll
                for (int rt = 0; rt < 4; rt++) {
                    const f16x8 a = *(const f16x8*)((const half_t*)bufA +
                              ((size_t)b * T_SZ + t0 + rt * 16 + (lane & 15)) * H_SZ + k0 + koff);
#pragma unroll
                    for (int cb = 0; cb < 8; cb++)
                        gac[rt][cb] = __builtin_amdgcn_mfma_f32_16x16x32_f16(a, bf[cb], gac[rt][cb], 0, 0, 0);
                }
            }
#pragma unroll
            for (int rt = 0; rt < 4; rt++) {
                const int rbase = t0 + rt * 16 + (lane >> 4) * 4;
#pragma unroll
                for (int cb = 0; cb < 8; cb++) {
                    const int col = 128 * w + 16 * cb + (lane & 15);
                    const float bsum = b_ih1[col] + b_hh1[col];
#pragma unroll
                    for (int r = 0; r < 4; r++)
                        bufB[((size_t)b * T_SZ + rbase + r) * H_SZ + col] =
                            (half_t)(gac[rt][cb][r] + bsum);
                }
            }
            __syncthreads();   // drain all waves' bufB stores (vmcnt0 at barrier)
            if (tid == 0)
                __hip_atomic_store(&flags1[b * NCH + chunk], 1u, __ATOMIC_RELEASE,
                                   __HIP_MEMORY_SCOPE_AGENT);
        }
        return;
    }

    // ---------- recurrence (roles 0 and 2) ----------
    const bool L1 = (role == 2);
    const float* Whh = L1 ? Whh1 : Whh0;

    const int q    = l >> 3;             // row-group within wave (0..7)
    const int sp   = l & 7;              // K-slice within wave (0..7)
    const int rowb = 128 * s + 16 * q;   // first of this lane's 16 rows

    unsigned int wreg[448];   // [pair c][row r] = wreg[c*16+r], pairs 0..27
#pragma unroll
    for (int r = 0; r < 16; r++) {
        const float* wrow = Whh + (size_t)(rowb + r) * H_SZ + 64 * sp;
#pragma unroll
        for (int c = 0; c < 28; c++)
            wreg[c * 16 + r] = pack_pair(wrow[2 * c], wrow[2 * c + 1]);
    }
#pragma unroll
    for (int p = 0; p < 4; p++) {        // pairs 28..31 spill to LDS
#pragma unroll
        for (int rq = 0; rq < 4; rq++) {
            const int c = 28 + p;
            unsigned int qv[4];
#pragma unroll
            for (int j = 0; j < 4; j++) {
                const float* wrow = Whh + (size_t)(rowb + 4 * rq + j) * H_SZ + 64 * sp;
                qv[j] = pack_pair(wrow[2 * c], wrow[2 * c + 1]);
            }
            uint4 v;
            v.x = qv[0]; v.y = qv[1]; v.z = qv[2]; v.w = qv[3];
            wlds[(p * 4 + rq) * 256 + tid] = v;
        }
    }

    const int e0 = rowb + 2 * sp;        // this thread's 2 output elements: e0, e0+1
    {
        const float* h0p = L1 ? h0_1 : h0_0;
        const int slice = e0 >> 6, off = e0 & 63;
        *(unsigned int*)&hpad[0][slice * 72 + off] = pack_pair(h0p[e0], h0p[e0 + 1]);
    }
    __syncthreads();

    unsigned short* xp16 = (unsigned short*)(L1 ? bufB : bufA);
    const size_t baseu = (size_t)b * T_SZ * H_SZ + e0;   // halfword index

    // read base: K-slice sp of each parity buffer (144 B stride, 16B-aligned;
    // the 8 broadcast addrs of each b128 cover disjoint 4-bank groups)
    const uint4* hp0 = (const uint4*)(&hpad[0][sp * 72]);
    const uint4* hp1 = (const uint4*)(&hpad[1][sp * 72]);
    unsigned int* hwr0 = (unsigned int*)&hpad[0][(e0 >> 6) * 72 + (e0 & 63)];
    unsigned int* hwr1 = (unsigned int*)&hpad[1][(e0 >> 6) * 72 + (e0 & 63)];

    const bool sb0 = (sp & 1) != 0;
    const bool sb1 = (sp & 2) != 0;
    const bool sb2 = (sp & 4) != 0;

#pragma unroll 1
    for (int chunk = 0; chunk < NCH; chunk++) {
        const int t0 = chunk * CH;
        if (L1) {
            if (tid == 0) {
                while (__hip_atomic_load(&flags1[b * NCH + chunk], __ATOMIC_ACQUIRE,
                                         __HIP_MEMORY_SCOPE_AGENT) == 0u)
                    __builtin_amdgcn_s_sleep(2);
            }
            __syncthreads();
        }
        unsigned int xw_next = *(const unsigned int*)(xp16 + baseu + (size_t)t0 * H_SZ);

#pragma unroll 1
        for (int tt = 0; tt < CH; tt++) {
            const int t = t0 + tt;
            const int par = tt & 1;
            const unsigned int xw = xw_next;
            if (tt + 1 < CH)
                xw_next = *(const unsigned int*)(xp16 + baseu + (size_t)(t + 1) * H_SZ);

            const uint4* hp = par ? hp1 : hp0;

            float acc[16];
#pragma unroll
            for (int r = 0; r < 16; r++) acc[r] = 0.f;

            // issue overflow pair 28 + h reads; consume staged (reads for
            // pair p land during the previous 64-fdot2 register block)
            uint4 wpa = wlds[0 * 256 + tid], wpb = wlds[1 * 256 + tid];
            uint4 wpc = wlds[2 * 256 + tid], wpd = wlds[3 * 256 + tid];
            uint4 hv7 = hp[7];
            uint4 hc  = hp[0];
            uint4 hn  = hp[1];

#define REGBLK(CC, HV) { \
                const unsigned int hx0 = (HV).x, hx1 = (HV).y, hx2 = (HV).z, hx3 = (HV).w; \
                _Pragma("unroll") \
                for (int r = 0; r < 16; r++) acc[r] = fdot2(wreg[((CC) * 4 + 0) * 16 + r], hx0, acc[r]); \
                _Pragma("unroll") \
                for (int r = 0; r < 16; r++) acc[r] = fdot2(wreg[((CC) * 4 + 1) * 16 + r], hx1, acc[r]); \
                _Pragma("unroll") \
                for (int r = 0; r < 16; r++) acc[r] = fdot2(wreg[((CC) * 4 + 2) * 16 + r], hx2, acc[r]); \
                _Pragma("unroll") \
                for (int r = 0; r < 16; r++) acc[r] = fdot2(wreg[((CC) * 4 + 3) * 16 + r], hx3, acc[r]); }
#define CONSUME(H2) { \
                acc[0]  = fdot2(wpa.x, (H2), acc[0]);  acc[1]  = fdot2(wpa.y, (H2), acc[1]); \
                acc[2]  = fdot2(wpa.z, (H2), acc[2]);  acc[3]  = fdot2(wpa.w, (H2), acc[3]); \
                acc[4]  = fdot2(wpb.x, (H2), acc[4]);  acc[5]  = fdot2(wpb.y, (H2), acc[5]); \
                acc[6]  = fdot2(wpb.z, (H2), acc[6]);  acc[7]  = fdot2(wpb.w, (H2), acc[7]); \
                acc[8]  = fdot2(wpc.x, (H2), acc[8]);  acc[9]  = fdot2(wpc.y, (H2), acc[9]); \
                acc[10] = fdot2(wpc.z, (H2), acc[10]); acc[11] = fdot2(wpc.w, (H2), acc[11]); \
                acc[12] = fdot2(wpd.x, (H2), acc[12]); acc[13] = fdot2(wpd.y, (H2), acc[13]); \
                acc[14] = fdot2(wpd.z, (H2), acc[14]); acc[15] = fdot2(wpd.w, (H2), acc[15]); }

            REGBLK(0, hc) CONSUME(hv7.x)
            wpa = wlds[4 * 256 + tid];  wpb = wlds[5 * 256 + tid];
            wpc = wlds[6 * 256 + tid];  wpd = wlds[7 * 256 + tid];
            hc = hn; hn = hp[2];
            REGBLK(1, hc) CONSUME(hv7.y)
            wpa = wlds[8 * 256 + tid];  wpb = wlds[9 * 256 + tid];
            wpc = wlds[10 * 256 + tid]; wpd = wlds[11 * 256 + tid];
            hc = hn; hn = hp[3];
            REGBLK(2, hc) CONSUME(hv7.z)
            wpa = wlds[12 * 256 + tid]; wpb = wlds[13 * 256 + tid];
            wpc = wlds[14 * 256 + tid]; wpd = wlds[15 * 256 + tid];
            hc = hn; hn = hp[4];
            REGBLK(3, hc) CONSUME(hv7.w)
            hc = hn; hn = hp[5];
            REGBLK(4, hc)
            hc = hn; hn = hp[6];
            REGBLK(5, hc)
            hc = hn;
            REGBLK(6, hc)
#undef REGBLK
#undef CONSUME

            // reduce over the 8 sp-lanes (VALU pipe only)
#pragma unroll
            for (int r = 0; r < 16; r++) {
                float a = acc[r];
                a = dpp_add<0x0B1>(a);   // + lane^1
                a = dpp_add<0x04E>(a);   // + lane^2
                a = dpp_add<0x141>(a);   // + lane^7
                acc[r] = a;
            }
            // lane keeps rows 2sp and 2sp+1
            float rsum0, rsum1;
            {
                float t0a = sb0 ? acc[2]  : acc[0];
                float t1a = sb0 ? acc[6]  : acc[4];
                float t2a = sb0 ? acc[10] : acc[8];
                float t3a = sb0 ? acc[14] : acc[12];
                float u0a = sb1 ? t1a : t0a;
                float u1a = sb1 ? t3a : t2a;
                rsum0 = sb2 ? u1a : u0a;
                float t0b = sb0 ? acc[3]  : acc[1];
                float t1b = sb0 ? acc[7]  : acc[5];
                float t2b = sb0 ? acc[11] : acc[9];
                float t3b = sb0 ? acc[15] : acc[13];
                float u0b = sb1 ? t1b : t0b;
                float u1b = sb1 ? t3b : t2b;
                rsum1 = sb2 ? u1b : u0b;
            }

            half_t xlo = __builtin_bit_cast(half_t, (unsigned short)(xw & 0xffffu));
            half_t xhi = __builtin_bit_cast(half_t, (unsigned short)(xw >> 16));
            float y0 = (float)xlo + rsum0;
            float y1 = (float)xhi + rsum1;
            float ex0 = __expf(2.0f * y0);
            float ex1 = __expf(2.0f * y1);
            float hn0 = 1.0f - 2.0f * fast_rcp(ex0 + 1.0f);
            float hn1 = 1.0f - 2.0f * fast_rcp(ex1 + 1.0f);
            unsigned int hpk = pack_pair(hn0, hn1);

            *(par ? hwr0 : hwr1) = hpk;   // next step's h (parity flip)
            if (!L1)
                *(unsigned int*)(xp16 + baseu + (size_t)t * H_SZ) = hpk;
            else if (t == T_SZ - 1)
                *(float2*)(hT + (size_t)b * H_SZ + e0) = make_float2(hn0, hn1);

            step_barrier();    // lgkmcnt(0) + s_barrier: NO vmcnt drain
        }
        if (!L1) {
            __syncthreads();   // real barrier: vmcnt0 drains this chunk's res stores
            if (tid == 0)
                __hip_atomic_store(&flags0[b * NCH + chunk], 1u, __ATOMIC_RELEASE,
                                   __HIP_MEMORY_SCOPE_AGENT);
        }
    }
}

// ---------------- head ----------------
__global__ __launch_bounds__(128) void head_fc(const float* __restrict__ hT,
                                               const float* __restrict__ Wfc,
                                               const float* __restrict__ bfc,
                                               float* __restrict__ out)
{
    __shared__ float hs[H_SZ];
    const int b = blockIdx.x, o = threadIdx.x;
    for (int i = o; i < H_SZ; i += 128) hs[i] = hT[(size_t)b * H_SZ + i];
    __syncthreads();
    const float4* w4 = (const float4*)(Wfc + (size_t)o * H_SZ);
    const float4* h4 = (const float4*)hs;
    float acc = 0.f;
#pragma unroll 4
    for (int k = 0; k < H_SZ / 4; k++) {
        float4 w = w4[k], h = h4[k];
        acc += w.x * h.x + w.y * h.y + w.z * h.z + w.w * h.w;
    }
    out[(size_t)b * O_SZ + o] = acc + bfc[o];
}

// ---------------- launch ----------------

extern "C" void kernel_launch(void* const* d_in, const int* in_sizes, int n_in,
                              void* d_out, int out_size, void* d_ws, size_t ws_size,
                              hipStream_t stream) {
    const float* x     = (const float*)d_in[0];
    const float* W_ih0 = (const float*)d_in[1];
    const float* W_hh0 = (const float*)d_in[2];
    const float* b_ih0 = (const float*)d_in[3];
    const float* b_hh0 = (const float*)d_in[4];
    const float* h0_0  = (const float*)d_in[5];
    const float* W_ih1 = (const float*)d_in[6];
    const float* W_hh1 = (const float*)d_in[7];
    const float* b_ih1 = (const float*)d_in[8];
    const float* b_hh1 = (const float*)d_in[9];
    const float* h0_1  = (const float*)d_in[10];
    const float* W_fc  = (const float*)d_in[11];
    const float* b_fc  = (const float*)d_in[12];

    char* ws = (char*)d_ws;
    size_t off = 0;
    const size_t bufElems = (size_t)B_SZ * T_SZ * H_SZ;          // 67,108,864
    half_t* bufA  = (half_t*)(ws + off); off += bufElems * 2;    // xp0 -> res (in place)
    half_t* bufB  = (half_t*)(ws + off); off += bufElems * 2;    // xp1 (per-chunk producer)
    half_t* Wih0h = (half_t*)(ws + off); off += (size_t)H_SZ * F_SZ * 2;
    half_t* Wih1h = (half_t*)(ws + off); off += (size_t)H_SZ * H_SZ * 2;
    float*  hTbuf = (float*)(ws + off);  off += (size_t)B_SZ * H_SZ * 4;
    const int FLAG_N = B_SZ * NCH;
    unsigned int* flags0 = (unsigned int*)(ws + off); off += (size_t)FLAG_N * 4;
    unsigned int* flags1 = (unsigned int*)(ws + off); off += (size_t)FLAG_N * 4;

    const int M = B_SZ * T_SZ;   // 131072

    zero_flags<<<(2 * FLAG_N + 255) / 256, 256, 0, stream>>>(flags0, 2 * FLAG_N);
    cvt_f32_f16<<<(H_SZ * F_SZ + 255) / 256, 256, 0, stream>>>(W_ih0, Wih0h, H_SZ * F_SZ);
    cvt_f32_f16<<<(H_SZ * H_SZ + 255) / 256, 256, 0, stream>>>(W_ih1, Wih1h, H_SZ * H_SZ);

    // xp0 = x @ W_ih0^T + b_ih0 + b_hh0
    gemm_xp<true, F_SZ><<<(M / 64) * 8, 256, 0, stream>>>(x, Wih0h, b_ih0, b_hh0, bufA);

    // pipelined: layer-0 rec + xp1 producer + layer-1 rec, all concurrent.
    // Cooperative launch guarantees all 192 blocks co-resident (flag spin +
    // 1-block/CU register footprint make this mandatory).
    {
        half_t* a0 = bufA;  half_t* a1 = bufB;
        const float* a2 = W_hh0;  const float* a3 = W_hh1;
        const half_t* a4 = Wih1h;
        const float* a5 = h0_0;   const float* a6 = h0_1;
        const float* a7 = b_ih1;  const float* a8 = b_hh1;
        float* a9 = hTbuf;
        unsigned int* a10 = flags0;  unsigned int* a11 = flags1;
        void* kargs[12] = {&a0, &a1, &a2, &a3, &a4, &a5, &a6, &a7, &a8, &a9, &a10, &a11};
        if (hipLaunchCooperativeKernel(rnn_mega, dim3(192), dim3(256),
                                       kargs, 0, stream) != hipSuccess) {
            // fallback: plain launch (192 blocks <= 256 CUs, dispatcher spreads)
            rnn_mega<<<192, 256, 0, stream>>>(bufA, bufB, W_hh0, W_hh1, Wih1h,
                                              h0_0, h0_1, b_ih1, b_hh1,
                                              hTbuf, flags0, flags1);
        }
    }

    head_fc<<<B_SZ, 128, 0, stream>>>(hTbuf, W_fc, b_fc, (float*)d_out);
}